// Round 6
// baseline (2478.104 us; speedup 1.0000x reference)
//
#include <hip/hip_runtime.h>

#define NN    100000   // nodes
#define NEDGE 100000   // edges per relation
#define NRELS 6
#define HIDD  256
#define NGR   128      // graphs
#define NKEY  (NRELS * NN)        // 600000 (rel,tgt) keys
#define NEDGT (NRELS * NEDGE)     // 600000 edges total
#define KTOT  (7 * HIDD)          // 1792
#define AF32_LD 260               // fp32 LDS row stride (16B-aligned, bank-spread)

typedef __bf16 bf16;
typedef __bf16 bf16x8 __attribute__((ext_vector_type(8)));
typedef float  f32x4  __attribute__((ext_vector_type(4)));
typedef float  f32x16 __attribute__((ext_vector_type(16)));

// ================= CSR build (key = rel*NN + tgt) =================
__global__ __launch_bounds__(256)
void hist_kernel(const int* __restrict__ edges, int* __restrict__ hist)
{
    int i = blockIdx.x * 256 + threadIdx.x;
    if (i >= NEDGT) return;
    int r = i / NEDGE;
    int e = i - r * NEDGE;
    int t = edges[r * (2 * NEDGE) + NEDGE + e];
    atomicAdd(&hist[r * NN + t], 1);
}

__global__ __launch_bounds__(256)
void scan_l0(const int* __restrict__ in, int* __restrict__ out, int* __restrict__ bsum, int n)
{
    __shared__ int sdata[256];
    const int t = threadIdx.x;
    const int base = blockIdx.x * 2048 + t * 8;
    int v[8]; int s = 0;
#pragma unroll
    for (int i = 0; i < 8; ++i) {
        int idx = base + i;
        int x = (idx < n) ? in[idx] : 0;
        v[i] = s; s += x;
    }
    sdata[t] = s;
    __syncthreads();
    for (int off = 1; off < 256; off <<= 1) {
        int y = (t >= off) ? sdata[t - off] : 0;
        __syncthreads();
        sdata[t] += y;
        __syncthreads();
    }
    int excl = sdata[t] - s;
#pragma unroll
    for (int i = 0; i < 8; ++i) {
        int idx = base + i;
        if (idx < n) out[idx] = excl + v[i];
    }
    if (t == 0) bsum[blockIdx.x] = sdata[255];
}

__global__ __launch_bounds__(256)
void scan_l1(int* __restrict__ bsum, int n)
{
    __shared__ int sdata[256];
    const int t = threadIdx.x;
    const int base = t * 8;
    int v[8]; int s = 0;
#pragma unroll
    for (int i = 0; i < 8; ++i) {
        int idx = base + i;
        int x = (idx < n) ? bsum[idx] : 0;
        v[i] = s; s += x;
    }
    sdata[t] = s;
    __syncthreads();
    for (int off = 1; off < 256; off <<= 1) {
        int y = (t >= off) ? sdata[t - off] : 0;
        __syncthreads();
        sdata[t] += y;
        __syncthreads();
    }
    int excl = sdata[t] - s;
#pragma unroll
    for (int i = 0; i < 8; ++i) {
        int idx = base + i;
        if (idx < n) bsum[idx] = excl + v[i];
    }
}

__global__ __launch_bounds__(256)
void scan_l2(int* __restrict__ offs, int* __restrict__ cursor, const int* __restrict__ bsum, int n)
{
    int idx = blockIdx.x * 256 + threadIdx.x;
    if (idx == 0) offs[NKEY] = NEDGT;
    if (idx >= n) return;
    int v = offs[idx] + bsum[idx >> 11];
    offs[idx] = v;
    cursor[idx] = v;
}

// epack = src | ((tgt & 31) << 20)   (src < 2^17; subtile bases are 32-aligned)
__global__ __launch_bounds__(256)
void scatter_kernel(const int* __restrict__ edges, int* __restrict__ cursor,
                    int* __restrict__ epack)
{
    int i = blockIdx.x * 256 + threadIdx.x;
    if (i >= NEDGT) return;
    int r = i / NEDGE;
    int e = i - r * NEDGE;
    int s = edges[r * (2 * NEDGE) + e];
    int t = edges[r * (2 * NEDGE) + NEDGE + e];
    int pos = atomicAdd(&cursor[r * NN + t], 1);
    epack[pos] = s | ((t & 31) << 20);
}

__global__ __launch_bounds__(256)
void invdeg_kernel(const int* __restrict__ hist, float* __restrict__ invdeg)
{
    int t = blockIdx.x * 256 + threadIdx.x;
    if (t >= NN) return;
    int d = 0;
#pragma unroll
    for (int r = 0; r < NRELS; ++r) d += hist[r * NN + t];
    invdeg[t] = 1.0f / fmaxf((float)d, 1.0f);
}

// ---------------- Wcat[n][seg*256+k]; both layers in one launch (z = layer) ----------------
__global__ __launch_bounds__(256)
void build_wcat(const float* __restrict__ Wr0, const float* __restrict__ Ws0,
                const float* __restrict__ Wr1, const float* __restrict__ Ws1,
                bf16* __restrict__ Wc0, bf16* __restrict__ Wc1)
{
    int seg = blockIdx.x;
    int k = blockIdx.y;
    int n = threadIdx.x;
    const float* Wr = blockIdx.z ? Wr1 : Wr0;
    const float* Ws = blockIdx.z ? Ws1 : Ws0;
    bf16* Wc = blockIdx.z ? Wc1 : Wc0;
    float v = (seg < 6) ? Wr[((size_t)seg << 16) + (k << 8) + n] : Ws[(k << 8) + n];
    Wc[(size_t)n * KTOT + seg * 256 + k] = (bf16)v;
}

// ---------------- fused RGCN layer ----------------
// grid ceil(NN/64), block 256 (4 waves). Per seg: two 32-row subtiles aggregated
// edge-parallel into fp32 LDS via ds_add_f32 (independent iterations -> pipelined),
// converted (xinvdeg) into a 64x256 bf16 A-tile (XOR-swizzled), then 16 MFMA k-steps
// with B frags streamed from L2-hot Wcat. L0 variant computes the type/sub embedding
// inline (hot tables) instead of reading a materialized h.
template<bool L0>
__global__ __launch_bounds__(256, 2)
void rgcn_fused(const bf16* __restrict__ hin,
                const int* __restrict__ xt, const int* __restrict__ xs,
                const float* __restrict__ temb, const float* __restrict__ semb,
                const bf16* __restrict__ Wcat, const float* __restrict__ bias,
                const float* __restrict__ invdeg, const int* __restrict__ offs,
                const int* __restrict__ epack, bf16* __restrict__ hout)
{
    const int m0 = blockIdx.x * 64;
    const int tid = threadIdx.x;
    const int lane = tid & 63;
    const int w = tid >> 6;
    const int l31 = lane & 31;
    const int lhi = lane >> 5;

    __shared__ float Af32[32 * AF32_LD];            // 32.5 KB (one subtile, fp32)
    __shared__ __align__(16) bf16 Abf[64 * HIDD];   // 32 KB (full tile, bf16 swizzled)

    f32x16 acc[2][2] = {};

    const int zr = tid >> 3;            // zero: row
    const int zc = (tid & 7) * 32;      // zero: col base
    const int cr = tid & 31;            // convert: row (bank-spread mapping)
    const int cg = tid >> 5;            // convert: octet group 0..7

    for (int seg = 0; seg < 7; ++seg) {
        for (int sub = 0; sub < 2; ++sub) {
            const int mb = m0 + sub * 32;
            __syncthreads();
            if (seg < 6) {
                // ---- zero fp32 accum ----
#pragma unroll
                for (int q = 0; q < 8; ++q)
                    *(f32x4*)&Af32[zr * AF32_LD + zc + q * 4] = (f32x4)0.f;
                __syncthreads();
                // ---- edge-parallel aggregation (wave w takes every 4th edge) ----
                if (mb < NN) {
                    const int st = offs[seg * NN + mb];
                    const int en = offs[seg * NN + mb + 32];
#pragma unroll 2
                    for (int e = st + w; e < en; e += 4) {
                        const int ef = __builtin_amdgcn_readfirstlane(e);
                        const int p = epack[ef];
                        const int s = p & 0xFFFFF;
                        const int tl = (p >> 20) & 31;
                        float v0, v1, v2, v3;
                        if (L0) {
                            const int a = xt[s], b = xs[s];
                            v0 = temb[a * 128 + lane];
                            v1 = temb[a * 128 + 64 + lane];
                            v2 = semb[b * 128 + lane];
                            v3 = semb[b * 128 + 64 + lane];
                        } else {
                            const bf16* hr = hin + ((size_t)s << 8);
                            v0 = (float)hr[lane];
                            v1 = (float)hr[64 + lane];
                            v2 = (float)hr[128 + lane];
                            v3 = (float)hr[192 + lane];
                        }
                        atomicAdd(&Af32[tl * AF32_LD + lane], v0);
                        atomicAdd(&Af32[tl * AF32_LD + 64 + lane], v1);
                        atomicAdd(&Af32[tl * AF32_LD + 128 + lane], v2);
                        atomicAdd(&Af32[tl * AF32_LD + 192 + lane], v3);
                    }
                }
                __syncthreads();
                // ---- convert: scale by invdeg, fp32 -> bf16 swizzled tile ----
                const int gr = mb + cr;
                const float inv = (gr < NN) ? invdeg[gr] : 0.f;
                const int row = sub * 32 + cr;
#pragma unroll
                for (int j = 0; j < 4; ++j) {
                    const int oct = cg * 4 + j;
                    bf16x8 o;
                    if (gr < NN) {
                        f32x4 x0 = *(const f32x4*)&Af32[cr * AF32_LD + oct * 8];
                        f32x4 x1 = *(const f32x4*)&Af32[cr * AF32_LD + oct * 8 + 4];
                        o[0] = (bf16)(x0[0] * inv); o[1] = (bf16)(x0[1] * inv);
                        o[2] = (bf16)(x0[2] * inv); o[3] = (bf16)(x0[3] * inv);
                        o[4] = (bf16)(x1[0] * inv); o[5] = (bf16)(x1[1] * inv);
                        o[6] = (bf16)(x1[2] * inv); o[7] = (bf16)(x1[3] * inv);
                    } else {
                        o = (bf16x8)(bf16)0.f;
                    }
                    const int u = row * 32 + (oct ^ cr);
                    *(bf16x8*)&Abf[u * 8] = o;
                }
            } else {
                // ---- seg 6: self term (copy h / inline embed) ----
                const int gr = mb + cr;
                const int row = sub * 32 + cr;
                int a = 0, b = 0;
                if (L0 && gr < NN) { a = xt[gr]; b = xs[gr]; }
#pragma unroll
                for (int j = 0; j < 4; ++j) {
                    const int oct = cg * 4 + j;
                    bf16x8 o;
                    if (gr < NN) {
                        if (L0) {
                            const int f0 = oct * 8;
                            const float* src = (f0 < 128) ? (temb + a * 128 + f0)
                                                          : (semb + b * 128 + (f0 - 128));
                            f32x4 x0 = *(const f32x4*)src;
                            f32x4 x1 = *(const f32x4*)(src + 4);
                            o[0] = (bf16)x0[0]; o[1] = (bf16)x0[1];
                            o[2] = (bf16)x0[2]; o[3] = (bf16)x0[3];
                            o[4] = (bf16)x1[0]; o[5] = (bf16)x1[1];
                            o[6] = (bf16)x1[2]; o[7] = (bf16)x1[3];
                        } else {
                            o = *(const bf16x8*)&hin[((size_t)gr << 8) + oct * 8];
                        }
                    } else {
                        o = (bf16x8)(bf16)0.f;
                    }
                    const int u = row * 32 + (oct ^ cr);
                    *(bf16x8*)&Abf[u * 8] = o;
                }
            }
        }
        __syncthreads();   // A-tile ready

        // ---- MFMA: 16 k-steps of 16; B direct from global (L2-hot Wcat) ----
        const bf16* const wb0 = Wcat + (size_t)(w * 64 + l31) * KTOT + seg * 256 + lhi * 8;
        const bf16* const wb1 = wb0 + (size_t)32 * KTOT;
#pragma unroll
        for (int step = 0; step < 16; ++step) {
            bf16x8 b0 = *(const bf16x8*)(wb0 + step * 16);
            bf16x8 b1 = *(const bf16x8*)(wb1 + step * 16);
            const int ku = step * 2 + lhi;
            bf16x8 a0 = *(const bf16x8*)&Abf[(l31 * 32 + (ku ^ l31)) * 8];
            bf16x8 a1 = *(const bf16x8*)&Abf[(((32 + l31) * 32) + (ku ^ l31)) * 8];
            acc[0][0] = __builtin_amdgcn_mfma_f32_32x32x16_bf16(a0, b0, acc[0][0], 0, 0, 0);
            acc[0][1] = __builtin_amdgcn_mfma_f32_32x32x16_bf16(a0, b1, acc[0][1], 0, 0, 0);
            acc[1][0] = __builtin_amdgcn_mfma_f32_32x32x16_bf16(a1, b0, acc[1][0], 0, 0, 0);
            acc[1][1] = __builtin_amdgcn_mfma_f32_32x32x16_bf16(a1, b1, acc[1][1], 0, 0, 0);
        }
    }

    // ---- epilogue: C col = w*64+ct*32+(lane&31), row = (reg&3)+8*(reg>>2)+4*(lane>>5) ----
    float bcol[2];
#pragma unroll
    for (int ct = 0; ct < 2; ++ct) bcol[ct] = bias[w * 64 + ct * 32 + l31];
#pragma unroll
    for (int rt = 0; rt < 2; ++rt) {
#pragma unroll
        for (int reg = 0; reg < 16; ++reg) {
            const int row = m0 + rt * 32 + (reg & 3) + 8 * (reg >> 2) + 4 * lhi;
            if (row < NN) {
#pragma unroll
                for (int ct = 0; ct < 2; ++ct) {
                    const int col = w * 64 + ct * 32 + l31;
                    float v = acc[rt][ct][reg] + bcol[ct];
                    hout[((size_t)row << 8) + col] = (bf16)fmaxf(v, 0.0f);
                }
            }
        }
    }
}

// ---------------- segmented mean-pool (batch_ids sorted) ----------------
#define PCHUNK 512
__global__ __launch_bounds__(256)
void pool_kernel(const bf16* __restrict__ h, const int* __restrict__ batch_ids,
                 float* __restrict__ pooled, float* __restrict__ cnt)
{
    const int n0 = blockIdx.x * PCHUNK;
    const int f = threadIdx.x;
    __shared__ int bid_l[PCHUNK];
    for (int i = f; i < PCHUNK; i += 256) {
        int n = n0 + i;
        bid_l[i] = (n < NN) ? batch_ids[n] : -1;
    }
    __syncthreads();
    const int nEnd = (NN - n0 < PCHUNK) ? (NN - n0) : PCHUNK;
    float s = 0.0f;
    int g = bid_l[0];
    int run = 0;
    for (int i = 0; i < nEnd; ++i) {
        int bg = bid_l[i];
        if (bg != g) {
            atomicAdd(&pooled[g * HIDD + f], s);
            if (f == 0) atomicAdd(&cnt[g], (float)run);
            s = 0.0f; run = 0; g = bg;
        }
        s += (float)h[(size_t)(n0 + i) * HIDD + f];
        run++;
    }
    if (run > 0) {
        atomicAdd(&pooled[g * HIDD + f], s);
        if (f == 0) atomicAdd(&cnt[g], (float)run);
    }
}

// ---------------- MLP head ----------------
__global__ __launch_bounds__(256)
void mlp_kernel(const float* __restrict__ pooled, const float* __restrict__ cnt,
                const float* __restrict__ pW1, const float* __restrict__ pb1,
                const float* __restrict__ pW2, const float* __restrict__ pb2,
                float* __restrict__ out)
{
    const int g = blockIdx.x;
    const int d = threadIdx.x;
    __shared__ float pn[HIDD];
    __shared__ float mid[HIDD];
    float c = fmaxf(cnt[g], 1.0f);
    pn[d] = pooled[g * HIDD + d] / c;
    __syncthreads();
    float s = pb1[d];
    for (int k = 0; k < HIDD; ++k) s = fmaf(pn[k], pW1[k * HIDD + d], s);
    mid[d] = fmaxf(s, 0.0f);
    __syncthreads();
    float s2 = pb2[d];
    for (int k = 0; k < HIDD; ++k) s2 = fmaf(mid[k], pW2[k * HIDD + d], s2);
    out[g * HIDD + d] = s2;
}

extern "C" void kernel_launch(void* const* d_in, const int* in_sizes, int n_in,
                              void* d_out, int out_size, void* d_ws, size_t ws_size,
                              hipStream_t stream)
{
    const int*   x_type    = (const int*)d_in[0];
    const int*   x_sub     = (const int*)d_in[1];
    const int*   edges     = (const int*)d_in[2];
    const int*   batch_ids = (const int*)d_in[3];
    const float* type_emb  = (const float*)d_in[5];
    const float* sub_emb   = (const float*)d_in[6];
    const float* W_rel0    = (const float*)d_in[7];
    const float* W_self0   = (const float*)d_in[8];
    const float* b0        = (const float*)d_in[9];
    const float* W_rel1    = (const float*)d_in[10];
    const float* W_self1   = (const float*)d_in[11];
    const float* b1        = (const float*)d_in[12];
    const float* pW1       = (const float*)d_in[13];
    const float* pb1       = (const float*)d_in[14];
    const float* pW2       = (const float*)d_in[15];
    const float* pb2       = (const float*)d_in[16];
    float* out = (float*)d_out;

    // workspace carve-up (~114 MB)
    char* p = (char*)d_ws;
    auto carve = [&](size_t bytes) { char* q = p; p += (bytes + 255) & ~255ull; return q; };
    bf16*  h1     = (bf16*) carve((size_t)NN * HIDD * sizeof(bf16));     // layer-0 out
    bf16*  h2     = (bf16*) carve((size_t)NN * HIDD * sizeof(bf16));     // layer-1 out
    bf16*  Wcat0  = (bf16*) carve((size_t)HIDD * KTOT * sizeof(bf16));
    bf16*  Wcat1  = (bf16*) carve((size_t)HIDD * KTOT * sizeof(bf16));
    float* invdeg = (float*)carve((size_t)NN * sizeof(float));
    int*   hist   = (int*)  carve((size_t)NKEY * sizeof(int));
    int*   offs   = (int*)  carve((size_t)(NKEY + 1) * sizeof(int));
    int*   cursor = (int*)  carve((size_t)NKEY * sizeof(int));
    int*   bsum   = (int*)  carve(2048 * sizeof(int));
    int*   epack  = (int*)  carve((size_t)NEDGT * sizeof(int));
    float* pooled = (float*)carve((size_t)NGR * HIDD * sizeof(float));   // 131072 B (256-mult)
    float* cnt    = (float*)carve((size_t)NGR * sizeof(float));          // adjacent to pooled

    hipMemsetAsync(hist, 0, (size_t)NKEY * sizeof(int), stream);
    hipMemsetAsync(pooled, 0, (size_t)(NGR * HIDD + NGR) * sizeof(float), stream);

    const int NB0 = (NKEY + 2047) / 2048;  // 293
    hist_kernel<<<(NEDGT + 255) / 256, 256, 0, stream>>>(edges, hist);
    scan_l0<<<NB0, 256, 0, stream>>>(hist, offs, bsum, NKEY);
    scan_l1<<<1, 256, 0, stream>>>(bsum, NB0);
    scan_l2<<<(NKEY + 255) / 256, 256, 0, stream>>>(offs, cursor, bsum, NKEY);
    scatter_kernel<<<(NEDGT + 255) / 256, 256, 0, stream>>>(edges, cursor, epack);
    invdeg_kernel<<<(NN + 255) / 256, 256, 0, stream>>>(hist, invdeg);

    dim3 wgrid(7, 256, 2);
    build_wcat<<<wgrid, 256, 0, stream>>>(W_rel0, W_self0, W_rel1, W_self1, Wcat0, Wcat1);

    const int FGRID = (NN + 63) / 64;   // 1563
    rgcn_fused<true><<<FGRID, 256, 0, stream>>>(h2 /*unused*/, x_type, x_sub, type_emb, sub_emb,
                                                Wcat0, b0, invdeg, offs, epack, h1);
    rgcn_fused<false><<<FGRID, 256, 0, stream>>>(h1, x_type, x_sub, type_emb, sub_emb,
                                                 Wcat1, b1, invdeg, offs, epack, h2);

    pool_kernel<<<(NN + PCHUNK - 1) / PCHUNK, 256, 0, stream>>>(h2, batch_ids, pooled, cnt);
    mlp_kernel<<<NGR, 256, 0, stream>>>(pooled, cnt, pW1, pb1, pW2, pb2, out);
}

// Round 7
// 1160.417 us; speedup vs baseline: 2.1355x; 2.1355x over previous
//
#include <hip/hip_runtime.h>

#define NN    100000   // nodes
#define NEDGE 100000   // edges per relation
#define NRELS 6
#define HIDD  256
#define NGR   128      // graphs
#define NKEY  (NRELS * NN)        // 600000 (rel,tgt) keys
#define NEDGT (NRELS * NEDGE)     // 600000 edges total
#define KTOT  (7 * HIDD)          // 1792

typedef __bf16 bf16;
typedef __bf16 bf16x4 __attribute__((ext_vector_type(4)));
typedef __bf16 bf16x8 __attribute__((ext_vector_type(8)));
typedef float  f32x4  __attribute__((ext_vector_type(4)));
typedef float  f32x16 __attribute__((ext_vector_type(16)));

// ================= CSR build (key = rel*NN + tgt) =================
__global__ __launch_bounds__(256)
void hist_kernel(const int* __restrict__ edges, int* __restrict__ hist)
{
    int i = blockIdx.x * 256 + threadIdx.x;
    if (i >= NEDGT) return;
    int r = i / NEDGE;
    int e = i - r * NEDGE;
    int t = edges[r * (2 * NEDGE) + NEDGE + e];
    atomicAdd(&hist[r * NN + t], 1);
}

__global__ __launch_bounds__(256)
void scan_l0(const int* __restrict__ in, int* __restrict__ out, int* __restrict__ bsum, int n)
{
    __shared__ int sdata[256];
    const int t = threadIdx.x;
    const int base = blockIdx.x * 2048 + t * 8;
    int v[8]; int s = 0;
#pragma unroll
    for (int i = 0; i < 8; ++i) {
        int idx = base + i;
        int x = (idx < n) ? in[idx] : 0;
        v[i] = s; s += x;
    }
    sdata[t] = s;
    __syncthreads();
    for (int off = 1; off < 256; off <<= 1) {
        int y = (t >= off) ? sdata[t - off] : 0;
        __syncthreads();
        sdata[t] += y;
        __syncthreads();
    }
    int excl = sdata[t] - s;
#pragma unroll
    for (int i = 0; i < 8; ++i) {
        int idx = base + i;
        if (idx < n) out[idx] = excl + v[i];
    }
    if (t == 0) bsum[blockIdx.x] = sdata[255];
}

__global__ __launch_bounds__(256)
void scan_l1(int* __restrict__ bsum, int n)
{
    __shared__ int sdata[256];
    const int t = threadIdx.x;
    const int base = t * 8;
    int v[8]; int s = 0;
#pragma unroll
    for (int i = 0; i < 8; ++i) {
        int idx = base + i;
        int x = (idx < n) ? bsum[idx] : 0;
        v[i] = s; s += x;
    }
    sdata[t] = s;
    __syncthreads();
    for (int off = 1; off < 256; off <<= 1) {
        int y = (t >= off) ? sdata[t - off] : 0;
        __syncthreads();
        sdata[t] += y;
        __syncthreads();
    }
    int excl = sdata[t] - s;
#pragma unroll
    for (int i = 0; i < 8; ++i) {
        int idx = base + i;
        if (idx < n) bsum[idx] = excl + v[i];
    }
}

// add block sums; cursor copy; sentinel; fused invdeg (hist still intact here)
__global__ __launch_bounds__(256)
void scan_l2(int* __restrict__ offs, int* __restrict__ cursor, const int* __restrict__ bsum,
             const int* __restrict__ hist, float* __restrict__ invdeg, int n)
{
    int idx = blockIdx.x * 256 + threadIdx.x;
    if (idx == 0) offs[NKEY] = NEDGT;
    if (idx < NN) {
        int d = 0;
#pragma unroll
        for (int r = 0; r < NRELS; ++r) d += hist[r * NN + idx];
        invdeg[idx] = 1.0f / fmaxf((float)d, 1.0f);
    }
    if (idx >= n) return;
    int v = offs[idx] + bsum[idx >> 11];
    offs[idx] = v;
    cursor[idx] = v;
}

__global__ __launch_bounds__(256)
void scatter_kernel(const int* __restrict__ edges, int* __restrict__ cursor,
                    int* __restrict__ sorted_src, int* __restrict__ sorted_tgt)
{
    int i = blockIdx.x * 256 + threadIdx.x;
    if (i >= NEDGT) return;
    int r = i / NEDGE;
    int e = i - r * NEDGE;
    int s = edges[r * (2 * NEDGE) + e];
    int t = edges[r * (2 * NEDGE) + NEDGE + e];
    int pos = atomicAdd(&cursor[r * NN + t], 1);
    sorted_src[pos] = s;
    sorted_tgt[pos] = t;
}

// ---------------- Wcat[n][seg*256+k]; both layers in one launch (z = layer) ----------------
__global__ __launch_bounds__(256)
void build_wcat(const float* __restrict__ Wr0, const float* __restrict__ Ws0,
                const float* __restrict__ Wr1, const float* __restrict__ Ws1,
                bf16* __restrict__ Wc0, bf16* __restrict__ Wc1)
{
    int seg = blockIdx.x;
    int k = blockIdx.y;
    int n = threadIdx.x;
    const float* Wr = blockIdx.z ? Wr1 : Wr0;
    const float* Ws = blockIdx.z ? Ws1 : Ws0;
    bf16* Wc = blockIdx.z ? Wc1 : Wc0;
    float v = (seg < 6) ? Wr[((size_t)seg << 16) + (k << 8) + n] : Ws[(k << 8) + n];
    Wc[(size_t)n * KTOT + seg * 256 + k] = (bf16)v;
}

// ---------------- fused RGCN layer (round-5 structure + batched prefetch + inline embed) ----------------
// grid ceil(NN/64), block 256 (4 waves). Wave w: output cols w*64..+63, all 64 rows;
// A-build: wave owns rows w*16..+16 = contiguous CSR edge range; edges consumed in
// batches of 8 (8 independent gathers in flight -> one stall per 8 edges); meta via
// v_readlane. A-tile in XOR-swizzled LDS; B frags straight from L2-hot Wcat.
template<bool L0>
__global__ __launch_bounds__(256, 4)
void rgcn_fused(const bf16* __restrict__ hin,
                const int* __restrict__ xt, const int* __restrict__ xs,
                const float* __restrict__ temb, const float* __restrict__ semb,
                const bf16* __restrict__ Wcat, const float* __restrict__ bias,
                const float* __restrict__ invdeg, const int* __restrict__ offs,
                const int* __restrict__ ssrc, const int* __restrict__ stgt,
                bf16* __restrict__ hout)
{
    const int m0 = blockIdx.x * 64;
    const int tid = threadIdx.x;
    const int lane = tid & 63;
    const int w = tid >> 6;
    const int l31 = lane & 31;
    const int lhi = lane >> 5;
    const int rbase_t = w * 16;

    __shared__ __align__(16) bf16 As[64 * HIDD];   // 32 KB

    f32x16 acc[2][2] = {};

    for (int seg = 0; seg < 7; ++seg) {
        __syncthreads();   // previous seg's MFMA reads of As complete

        // ---- zero this wave's As rows ----
#pragma unroll
        for (int z = 0; z < 8; ++z) {
            const int row = rbase_t + z * 2 + lhi;
            const int unit = row * 32 + (l31 ^ (row & 7));
            *(bf16x8*)&As[unit * 8] = (bf16x8)(bf16)0.0f;
        }

        if (seg == 6) {
            // ---- self segment: copy h rows / inline embed ----
#pragma unroll
            for (int z = 0; z < 8; ++z) {
                const int row = rbase_t + z * 2 + lhi;
                const int gr = m0 + row;
                if (gr < NN) {
                    bf16x8 o;
                    if (L0) {
                        const int f0 = l31 * 8;
                        const float* src = (f0 < 128) ? (temb + xt[gr] * 128 + f0)
                                                      : (semb + xs[gr] * 128 + (f0 - 128));
                        f32x4 x0 = *(const f32x4*)src;
                        f32x4 x1 = *(const f32x4*)(src + 4);
                        o[0] = (bf16)x0[0]; o[1] = (bf16)x0[1];
                        o[2] = (bf16)x0[2]; o[3] = (bf16)x0[3];
                        o[4] = (bf16)x1[0]; o[5] = (bf16)x1[1];
                        o[6] = (bf16)x1[2]; o[7] = (bf16)x1[3];
                    } else {
                        o = *(const bf16x8*)(hin + ((size_t)gr << 8) + l31 * 8);
                    }
                    const int unit = row * 32 + (l31 ^ (row & 7));
                    *(bf16x8*)&As[unit * 8] = o;
                }
            }
        } else {
            // ---- aggregation for rows [m0+rbase_t, m0+rbase_t+16) ----
            const int gr0 = m0 + rbase_t;
            if (gr0 < NN) {
                const int rend = (gr0 + 16 < NN) ? (gr0 + 16) : NN;
                int st = offs[seg * NN + gr0];
                const int en = offs[seg * NN + rend];

                float a0 = 0.f, a1 = 0.f, a2 = 0.f, a3 = 0.f;
                int cur = -1;   // current tile-local row (wave-uniform)

                while (st < en) {
                    const int cnt = (en - st < 64) ? (en - st) : 64;
                    const int sv = (lane < cnt) ? ssrc[st + lane] : 0;
                    const int tv = (lane < cnt) ? stgt[st + lane] : 0;
                    int at = 0, bt = 0;
                    if (L0) { at = xt[sv]; bt = xs[sv]; }   // parallel 64-wide gathers (L2)

                    for (int base = 0; base < cnt; base += 8) {
                        // issue up to 8 independent feature-row gathers
                        f32x4  fb[8];
                        bf16x4 hb[8];
#pragma unroll
                        for (int p = 0; p < 8; ++p) {
                            const int i = base + p;
                            if (i < cnt) {
                                if (L0) {
                                    const int a = __builtin_amdgcn_readlane(at, i);
                                    const int b = __builtin_amdgcn_readlane(bt, i);
                                    const float* srcp = (lane < 32)
                                        ? temb + a * 128 + lane * 4
                                        : semb + b * 128 + (lane - 32) * 4;
                                    fb[p] = *(const f32x4*)srcp;
                                } else {
                                    const int s = __builtin_amdgcn_readlane(sv, i);
                                    hb[p] = *(const bf16x4*)(hin + ((size_t)s << 8) + lane * 4);
                                }
                            }
                        }
                        // consume
#pragma unroll
                        for (int p = 0; p < 8; ++p) {
                            const int i = base + p;
                            if (i < cnt) {
                                const int t = __builtin_amdgcn_readlane(tv, i) - m0;
                                if (t != cur) {
                                    if (cur >= 0) {
                                        const float inv = invdeg[m0 + cur];
                                        bf16x4 o;
                                        o.x = (bf16)(a0 * inv); o.y = (bf16)(a1 * inv);
                                        o.z = (bf16)(a2 * inv); o.w = (bf16)(a3 * inv);
                                        const int unit = cur * 32 + ((lane >> 1) ^ (cur & 7));
                                        *(bf16x4*)&As[unit * 8 + (lane & 1) * 4] = o;
                                    }
                                    cur = t; a0 = a1 = a2 = a3 = 0.f;
                                }
                                if (L0) {
                                    a0 += fb[p][0]; a1 += fb[p][1];
                                    a2 += fb[p][2]; a3 += fb[p][3];
                                } else {
                                    a0 += (float)hb[p].x; a1 += (float)hb[p].y;
                                    a2 += (float)hb[p].z; a3 += (float)hb[p].w;
                                }
                            }
                        }
                    }
                    st += cnt;
                }
                if (cur >= 0) {
                    const float inv = invdeg[m0 + cur];
                    bf16x4 o;
                    o.x = (bf16)(a0 * inv); o.y = (bf16)(a1 * inv);
                    o.z = (bf16)(a2 * inv); o.w = (bf16)(a3 * inv);
                    const int unit = cur * 32 + ((lane >> 1) ^ (cur & 7));
                    *(bf16x4*)&As[unit * 8 + (lane & 1) * 4] = o;
                }
            }
        }

        __syncthreads();   // As ready for all waves

        // ---- MFMA: 16 k-steps of 16; B frags straight from global (L2-hot Wcat) ----
        const bf16* const wb0 = Wcat + (size_t)(w * 64 + l31) * KTOT + seg * 256 + lhi * 8;
        const bf16* const wb1 = wb0 + (size_t)32 * KTOT;
#pragma unroll
        for (int step = 0; step < 16; ++step) {
            bf16x8 b0 = *(const bf16x8*)(wb0 + step * 16);
            bf16x8 b1 = *(const bf16x8*)(wb1 + step * 16);
            const int ku = step * 2 + lhi;
            bf16x8 a0 = *(const bf16x8*)&As[(l31 * 32 + (ku ^ (l31 & 7))) * 8];
            bf16x8 a1 = *(const bf16x8*)&As[((32 + l31) * 32 + (ku ^ (l31 & 7))) * 8];
            acc[0][0] = __builtin_amdgcn_mfma_f32_32x32x16_bf16(a0, b0, acc[0][0], 0, 0, 0);
            acc[0][1] = __builtin_amdgcn_mfma_f32_32x32x16_bf16(a0, b1, acc[0][1], 0, 0, 0);
            acc[1][0] = __builtin_amdgcn_mfma_f32_32x32x16_bf16(a1, b0, acc[1][0], 0, 0, 0);
            acc[1][1] = __builtin_amdgcn_mfma_f32_32x32x16_bf16(a1, b1, acc[1][1], 0, 0, 0);
        }
    }

    // ---- epilogue: C col = w*64+ct*32+(lane&31), row = (reg&3)+8*(reg>>2)+4*(lane>>5) ----
    float bcol[2];
#pragma unroll
    for (int ct = 0; ct < 2; ++ct) bcol[ct] = bias[w * 64 + ct * 32 + l31];
#pragma unroll
    for (int rt = 0; rt < 2; ++rt) {
#pragma unroll
        for (int reg = 0; reg < 16; ++reg) {
            const int row = m0 + rt * 32 + (reg & 3) + 8 * (reg >> 2) + 4 * lhi;
            if (row < NN) {
#pragma unroll
                for (int ct = 0; ct < 2; ++ct) {
                    const int col = w * 64 + ct * 32 + l31;
                    float v = acc[rt][ct][reg] + bcol[ct];
                    hout[((size_t)row << 8) + col] = (bf16)fmaxf(v, 0.0f);
                }
            }
        }
    }
}

// ---------------- segmented mean-pool (batch_ids sorted) ----------------
#define PCHUNK 512
__global__ __launch_bounds__(256)
void pool_kernel(const bf16* __restrict__ h, const int* __restrict__ batch_ids,
                 float* __restrict__ pooled, float* __restrict__ cnt)
{
    const int n0 = blockIdx.x * PCHUNK;
    const int f = threadIdx.x;
    __shared__ int bid_l[PCHUNK];
    for (int i = f; i < PCHUNK; i += 256) {
        int n = n0 + i;
        bid_l[i] = (n < NN) ? batch_ids[n] : -1;
    }
    __syncthreads();
    const int nEnd = (NN - n0 < PCHUNK) ? (NN - n0) : PCHUNK;
    float s = 0.0f;
    int g = bid_l[0];
    int run = 0;
    for (int i = 0; i < nEnd; ++i) {
        int bg = bid_l[i];
        if (bg != g) {
            atomicAdd(&pooled[g * HIDD + f], s);
            if (f == 0) atomicAdd(&cnt[g], (float)run);
            s = 0.0f; run = 0; g = bg;
        }
        s += (float)h[(size_t)(n0 + i) * HIDD + f];
        run++;
    }
    if (run > 0) {
        atomicAdd(&pooled[g * HIDD + f], s);
        if (f == 0) atomicAdd(&cnt[g], (float)run);
    }
}

// ---------------- MLP head ----------------
__global__ __launch_bounds__(256)
void mlp_kernel(const float* __restrict__ pooled, const float* __restrict__ cnt,
                const float* __restrict__ pW1, const float* __restrict__ pb1,
                const float* __restrict__ pW2, const float* __restrict__ pb2,
                float* __restrict__ out)
{
    const int g = blockIdx.x;
    const int d = threadIdx.x;
    __shared__ float pn[HIDD];
    __shared__ float mid[HIDD];
    float c = fmaxf(cnt[g], 1.0f);
    pn[d] = pooled[g * HIDD + d] / c;
    __syncthreads();
    float s = pb1[d];
    for (int k = 0; k < HIDD; ++k) s = fmaf(pn[k], pW1[k * HIDD + d], s);
    mid[d] = fmaxf(s, 0.0f);
    __syncthreads();
    float s2 = pb2[d];
    for (int k = 0; k < HIDD; ++k) s2 = fmaf(mid[k], pW2[k * HIDD + d], s2);
    out[g * HIDD + d] = s2;
}

extern "C" void kernel_launch(void* const* d_in, const int* in_sizes, int n_in,
                              void* d_out, int out_size, void* d_ws, size_t ws_size,
                              hipStream_t stream)
{
    const int*   x_type    = (const int*)d_in[0];
    const int*   x_sub     = (const int*)d_in[1];
    const int*   edges     = (const int*)d_in[2];
    const int*   batch_ids = (const int*)d_in[3];
    const float* type_emb  = (const float*)d_in[5];
    const float* sub_emb   = (const float*)d_in[6];
    const float* W_rel0    = (const float*)d_in[7];
    const float* W_self0   = (const float*)d_in[8];
    const float* b0        = (const float*)d_in[9];
    const float* W_rel1    = (const float*)d_in[10];
    const float* W_self1   = (const float*)d_in[11];
    const float* b1        = (const float*)d_in[12];
    const float* pW1       = (const float*)d_in[13];
    const float* pb1       = (const float*)d_in[14];
    const float* pW2       = (const float*)d_in[15];
    const float* pb2       = (const float*)d_in[16];
    float* out = (float*)d_out;

    // workspace carve-up (~118 MB)
    char* p = (char*)d_ws;
    auto carve = [&](size_t bytes) { char* q = p; p += (bytes + 255) & ~255ull; return q; };
    bf16*  h1     = (bf16*) carve((size_t)NN * HIDD * sizeof(bf16));     // layer-0 out
    bf16*  h2     = (bf16*) carve((size_t)NN * HIDD * sizeof(bf16));     // layer-1 out
    bf16*  Wcat0  = (bf16*) carve((size_t)HIDD * KTOT * sizeof(bf16));
    bf16*  Wcat1  = (bf16*) carve((size_t)HIDD * KTOT * sizeof(bf16));
    float* invdeg = (float*)carve((size_t)NN * sizeof(float));
    int*   hist   = (int*)  carve((size_t)NKEY * sizeof(int));
    int*   offs   = (int*)  carve((size_t)(NKEY + 1) * sizeof(int));
    int*   cursor = (int*)  carve((size_t)NKEY * sizeof(int));
    int*   bsum   = (int*)  carve(2048 * sizeof(int));
    int*   ssrc   = (int*)  carve((size_t)NEDGT * sizeof(int));
    int*   stgt   = (int*)  carve((size_t)NEDGT * sizeof(int));
    float* pooled = (float*)carve((size_t)NGR * HIDD * sizeof(float));   // 256-mult
    float* cnt    = (float*)carve((size_t)NGR * sizeof(float));          // adjacent

    hipMemsetAsync(hist, 0, (size_t)NKEY * sizeof(int), stream);
    hipMemsetAsync(pooled, 0, (size_t)(NGR * HIDD + NGR) * sizeof(float), stream);

    const int NB0 = (NKEY + 2047) / 2048;  // 293
    hist_kernel<<<(NEDGT + 255) / 256, 256, 0, stream>>>(edges, hist);
    scan_l0<<<NB0, 256, 0, stream>>>(hist, offs, bsum, NKEY);
    scan_l1<<<1, 256, 0, stream>>>(bsum, NB0);
    scan_l2<<<(NKEY + 255) / 256, 256, 0, stream>>>(offs, cursor, bsum, hist, invdeg, NKEY);
    scatter_kernel<<<(NEDGT + 255) / 256, 256, 0, stream>>>(edges, cursor, ssrc, stgt);

    dim3 wgrid(7, 256, 2);
    build_wcat<<<wgrid, 256, 0, stream>>>(W_rel0, W_self0, W_rel1, W_self1, Wcat0, Wcat1);

    const int FGRID = (NN + 63) / 64;   // 1563
    rgcn_fused<true><<<FGRID, 256, 0, stream>>>(h2 /*unused*/, x_type, x_sub, type_emb, sub_emb,
                                                Wcat0, b0, invdeg, offs, ssrc, stgt, h1);
    rgcn_fused<false><<<FGRID, 256, 0, stream>>>(h1, x_type, x_sub, type_emb, sub_emb,
                                                 Wcat1, b1, invdeg, offs, ssrc, stgt, h2);

    pool_kernel<<<(NN + PCHUNK - 1) / PCHUNK, 256, 0, stream>>>(h2, batch_ids, pooled, cnt);
    mlp_kernel<<<NGR, 256, 0, stream>>>(pooled, cnt, pW1, pb1, pW2, pb2, out);
}

// Round 9
// 841.160 us; speedup vs baseline: 2.9461x; 1.3795x over previous
//
#include <hip/hip_runtime.h>

#define NN    100000   // nodes
#define NEDGE 100000   // edges per relation
#define NRELS 6
#define HIDD  256
#define NGR   128      // graphs
#define NKEY  (NRELS * NN)        // 600000 (rel,tgt) keys
#define NEDGT (NRELS * NEDGE)     // 600000 edges total
#define KTOT  (7 * HIDD)          // 1792
#define WFRAG_ELEMS (4 * 7 * 16 * 2 * 64 * 8)   // 458752 bf16 per layer

typedef __bf16 bf16;
typedef __bf16 bf16x4 __attribute__((ext_vector_type(4)));
typedef __bf16 bf16x8 __attribute__((ext_vector_type(8)));
typedef float  f32x4  __attribute__((ext_vector_type(4)));
typedef float  f32x16 __attribute__((ext_vector_type(16)));

// ================= CSR build (key = rel*NN + tgt) =================
__global__ __launch_bounds__(256)
void hist_kernel(const int* __restrict__ edges, int* __restrict__ hist)
{
    int i = blockIdx.x * 256 + threadIdx.x;
    if (i >= NEDGT) return;
    int r = i / NEDGE;
    int e = i - r * NEDGE;
    int t = edges[r * (2 * NEDGE) + NEDGE + e];
    atomicAdd(&hist[r * NN + t], 1);
}

__global__ __launch_bounds__(256)
void scan_l0(const int* __restrict__ in, int* __restrict__ out, int* __restrict__ bsum, int n)
{
    __shared__ int sdata[256];
    const int t = threadIdx.x;
    const int base = blockIdx.x * 2048 + t * 8;
    int v[8]; int s = 0;
#pragma unroll
    for (int i = 0; i < 8; ++i) {
        int idx = base + i;
        int x = (idx < n) ? in[idx] : 0;
        v[i] = s; s += x;
    }
    sdata[t] = s;
    __syncthreads();
    for (int off = 1; off < 256; off <<= 1) {
        int y = (t >= off) ? sdata[t - off] : 0;
        __syncthreads();
        sdata[t] += y;
        __syncthreads();
    }
    int excl = sdata[t] - s;
#pragma unroll
    for (int i = 0; i < 8; ++i) {
        int idx = base + i;
        if (idx < n) out[idx] = excl + v[i];
    }
    if (t == 0) bsum[blockIdx.x] = sdata[255];
}

__global__ __launch_bounds__(256)
void scan_l1(int* __restrict__ bsum, int n)
{
    __shared__ int sdata[256];
    const int t = threadIdx.x;
    const int base = t * 8;
    int v[8]; int s = 0;
#pragma unroll
    for (int i = 0; i < 8; ++i) {
        int idx = base + i;
        int x = (idx < n) ? bsum[idx] : 0;
        v[i] = s; s += x;
    }
    sdata[t] = s;
    __syncthreads();
    for (int off = 1; off < 256; off <<= 1) {
        int y = (t >= off) ? sdata[t - off] : 0;
        __syncthreads();
        sdata[t] += y;
        __syncthreads();
    }
    int excl = sdata[t] - s;
#pragma unroll
    for (int i = 0; i < 8; ++i) {
        int idx = base + i;
        if (idx < n) bsum[idx] = excl + v[i];
    }
}

// add block sums; cursor copy; sentinel; fused invdeg
__global__ __launch_bounds__(256)
void scan_l2(int* __restrict__ offs, int* __restrict__ cursor, const int* __restrict__ bsum,
             const int* __restrict__ hist, float* __restrict__ invdeg, int n)
{
    int idx = blockIdx.x * 256 + threadIdx.x;
    if (idx == 0) offs[NKEY] = NEDGT;
    if (idx < NN) {
        int d = 0;
#pragma unroll
        for (int r = 0; r < NRELS; ++r) d += hist[r * NN + idx];
        invdeg[idx] = 1.0f / fmaxf((float)d, 1.0f);
    }
    if (idx >= n) return;
    int v = offs[idx] + bsum[idx >> 11];
    offs[idx] = v;
    cursor[idx] = v;
}

__global__ __launch_bounds__(256)
void scatter_kernel(const int* __restrict__ edges, int* __restrict__ cursor,
                    int* __restrict__ sorted_src, int* __restrict__ sorted_tgt)
{
    int i = blockIdx.x * 256 + threadIdx.x;
    if (i >= NEDGT) return;
    int r = i / NEDGE;
    int e = i - r * NEDGE;
    int s = edges[r * (2 * NEDGE) + e];
    int t = edges[r * (2 * NEDGE) + NEDGE + e];
    int pos = atomicAdd(&cursor[r * NN + t], 1);
    sorted_src[pos] = s;
    sorted_tgt[pos] = t;
}

// ---------------- Wfrag: B pre-swizzled into MFMA fragment order ----------------
// Wfrag[(((w*7+seg)*16+step)*2+ct)*64 + lane] (bf16x8 units)
//   = B-row n = w*64+ct*32+(lane&31), k_local = step*16 + (lane>>5)*8 .. +8
// where B[n][k] = W[k][n], W = per-seg 256x256 matrix. A wave's MFMA B-load
// becomes one contiguous 1KB read.
__global__ __launch_bounds__(256)
void build_wfrag(const float* __restrict__ Wr0, const float* __restrict__ Ws0,
                 const float* __restrict__ Wr1, const float* __restrict__ Ws1,
                 bf16* __restrict__ Wf0, bf16* __restrict__ Wf1)
{
    const int seg = blockIdx.x;     // 0..6
    const int step = blockIdx.y;    // 0..15
    const int layer = blockIdx.z;   // 0..1
    const int tid = threadIdx.x;
    const int w = tid >> 6;
    const int lane = tid & 63;
    const int l31 = lane & 31;
    const int lhi = lane >> 5;

    const float* Wr = layer ? Wr1 : Wr0;
    const float* Ws = layer ? Ws1 : Ws0;
    const float* src = (seg < 6) ? (Wr + ((size_t)seg << 16)) : Ws;
    bf16* Wf = layer ? Wf1 : Wf0;

    const int kb = step * 16 + lhi * 8;   // SEGMENT-LOCAL k (bug fix vs round 8)
#pragma unroll
    for (int ct = 0; ct < 2; ++ct) {
        const int n = w * 64 + ct * 32 + l31;
        bf16x8 o;
#pragma unroll
        for (int j = 0; j < 8; ++j)
            o[j] = (bf16)src[(size_t)(kb + j) * 256 + n];
        const size_t fb_idx = (size_t)(((w * 7 + seg) * 16 + step) * 2 + ct) * 64 + lane;
        *(bf16x8*)(Wf + fb_idx * 8) = o;
    }
}

// ---------------- fused RGCN layer ----------------
// grid ceil(NN/64), block 256 (4 waves). Wave w: output cols w*64..+63, all 64 rows.
// A-build: wave owns rows w*16..+16 = contiguous CSR edge range; depth-4 gather
// pipeline (4 independent loads in flight, small register cost -> no spill);
// meta via v_readlane. A-tile XOR-swizzled LDS; B frags = coalesced 1KB Wfrag reads.
template<bool L0>
__global__ __launch_bounds__(256, 3)
void rgcn_fused(const bf16* __restrict__ hin,
                const int* __restrict__ xt, const int* __restrict__ xs,
                const float* __restrict__ temb, const float* __restrict__ semb,
                const bf16* __restrict__ Wfrag, const float* __restrict__ bias,
                const float* __restrict__ invdeg, const int* __restrict__ offs,
                const int* __restrict__ ssrc, const int* __restrict__ stgt,
                bf16* __restrict__ hout)
{
    const int m0 = blockIdx.x * 64;
    const int tid = threadIdx.x;
    const int lane = tid & 63;
    const int w = tid >> 6;
    const int l31 = lane & 31;
    const int lhi = lane >> 5;
    const int rbase_t = w * 16;

    __shared__ __align__(16) bf16 As[64 * HIDD];   // 32 KB

    f32x16 acc[2][2] = {};

    for (int seg = 0; seg < 7; ++seg) {
        __syncthreads();   // previous seg's MFMA reads of As complete

        // ---- zero this wave's As rows ----
#pragma unroll
        for (int z = 0; z < 8; ++z) {
            const int row = rbase_t + z * 2 + lhi;
            const int unit = row * 32 + (l31 ^ (row & 7));
            *(bf16x8*)&As[unit * 8] = (bf16x8)(bf16)0.0f;
        }

        if (seg == 6) {
            // ---- self segment: copy h rows / inline embed ----
#pragma unroll
            for (int z = 0; z < 8; ++z) {
                const int row = rbase_t + z * 2 + lhi;
                const int gr = m0 + row;
                if (gr < NN) {
                    bf16x8 o;
                    if (L0) {
                        const int f0 = l31 * 8;
                        const float* src = (f0 < 128) ? (temb + xt[gr] * 128 + f0)
                                                      : (semb + xs[gr] * 128 + (f0 - 128));
                        f32x4 x0 = *(const f32x4*)src;
                        f32x4 x1 = *(const f32x4*)(src + 4);
                        o[0] = (bf16)x0[0]; o[1] = (bf16)x0[1];
                        o[2] = (bf16)x0[2]; o[3] = (bf16)x0[3];
                        o[4] = (bf16)x1[0]; o[5] = (bf16)x1[1];
                        o[6] = (bf16)x1[2]; o[7] = (bf16)x1[3];
                    } else {
                        o = *(const bf16x8*)(hin + ((size_t)gr << 8) + l31 * 8);
                    }
                    const int unit = row * 32 + (l31 ^ (row & 7));
                    *(bf16x8*)&As[unit * 8] = o;
                }
            }
        } else {
            // ---- aggregation for rows [m0+rbase_t, m0+rbase_t+16) ----
            const int gr0 = m0 + rbase_t;
            if (gr0 < NN) {
                const int rend = (gr0 + 16 < NN) ? (gr0 + 16) : NN;
                int st = offs[seg * NN + gr0];
                const int en = offs[seg * NN + rend];

                float a0 = 0.f, a1 = 0.f, a2 = 0.f, a3 = 0.f;
                int cur = -1;   // current tile-local row (wave-uniform)

                while (st < en) {
                    const int cnt = (en - st < 64) ? (en - st) : 64;
                    const int sv = (lane < cnt) ? ssrc[st + lane] : 0;
                    const int tv = (lane < cnt) ? stgt[st + lane] : 0;
                    int at = 0, bt = 0;
                    if (L0) { at = xt[sv]; bt = xs[sv]; }   // 64-wide parallel gathers

                    for (int base = 0; base < cnt; base += 4) {
                        // issue up to 4 independent feature-row gathers
                        f32x4  fb[4];
                        bf16x4 hb[4];
#pragma unroll
                        for (int p = 0; p < 4; ++p) {
                            const int i = base + p;
                            if (i < cnt) {
                                if (L0) {
                                    const int a = __builtin_amdgcn_readlane(at, i);
                                    const int b = __builtin_amdgcn_readlane(bt, i);
                                    const float* srcp = (lane < 32)
                                        ? temb + a * 128 + lane * 4
                                        : semb + b * 128 + (lane - 32) * 4;
                                    fb[p] = *(const f32x4*)srcp;
                                } else {
                                    const int s = __builtin_amdgcn_readlane(sv, i);
                                    hb[p] = *(const bf16x4*)(hin + ((size_t)s << 8) + lane * 4);
                                }
                            }
                        }
                        // consume
#pragma unroll
                        for (int p = 0; p < 4; ++p) {
                            const int i = base + p;
                            if (i < cnt) {
                                const int t = __builtin_amdgcn_readlane(tv, i) - m0;
                                if (t != cur) {
                                    if (cur >= 0) {
                                        const float inv = invdeg[m0 + cur];
                                        bf16x4 o;
                                        o.x = (bf16)(a0 * inv); o.y = (bf16)(a1 * inv);
                                        o.z = (bf16)(a2 * inv); o.w = (bf16)(a3 * inv);
                                        const int unit = cur * 32 + ((lane >> 1) ^ (cur & 7));
                                        *(bf16x4*)&As[unit * 8 + (lane & 1) * 4] = o;
                                    }
                                    cur = t; a0 = a1 = a2 = a3 = 0.f;
                                }
                                if (L0) {
                                    a0 += fb[p][0]; a1 += fb[p][1];
                                    a2 += fb[p][2]; a3 += fb[p][3];
                                } else {
                                    a0 += (float)hb[p].x; a1 += (float)hb[p].y;
                                    a2 += (float)hb[p].z; a3 += (float)hb[p].w;
                                }
                            }
                        }
                    }
                    st += cnt;
                }
                if (cur >= 0) {
                    const float inv = invdeg[m0 + cur];
                    bf16x4 o;
                    o.x = (bf16)(a0 * inv); o.y = (bf16)(a1 * inv);
                    o.z = (bf16)(a2 * inv); o.w = (bf16)(a3 * inv);
                    const int unit = cur * 32 + ((lane >> 1) ^ (cur & 7));
                    *(bf16x4*)&As[unit * 8 + (lane & 1) * 4] = o;
                }
            }
        }

        __syncthreads();   // As ready for all waves

        // ---- MFMA: 16 k-steps of 16; B frags = contiguous 1KB reads from Wfrag ----
        const bf16* const wseg = Wfrag + ((size_t)((w * 7 + seg) * 16) * 2 * 64) * 8;
#pragma unroll
        for (int step = 0; step < 16; ++step) {
            bf16x8 b0 = *(const bf16x8*)(wseg + ((size_t)(step * 2 + 0) * 64 + lane) * 8);
            bf16x8 b1 = *(const bf16x8*)(wseg + ((size_t)(step * 2 + 1) * 64 + lane) * 8);
            const int ku = step * 2 + lhi;
            bf16x8 a0 = *(const bf16x8*)&As[(l31 * 32 + (ku ^ (l31 & 7))) * 8];
            bf16x8 a1 = *(const bf16x8*)&As[((32 + l31) * 32 + (ku ^ (l31 & 7))) * 8];
            acc[0][0] = __builtin_amdgcn_mfma_f32_32x32x16_bf16(a0, b0, acc[0][0], 0, 0, 0);
            acc[0][1] = __builtin_amdgcn_mfma_f32_32x32x16_bf16(a0, b1, acc[0][1], 0, 0, 0);
            acc[1][0] = __builtin_amdgcn_mfma_f32_32x32x16_bf16(a1, b0, acc[1][0], 0, 0, 0);
            acc[1][1] = __builtin_amdgcn_mfma_f32_32x32x16_bf16(a1, b1, acc[1][1], 0, 0, 0);
        }
    }

    // ---- epilogue: C col = w*64+ct*32+(lane&31), row = (reg&3)+8*(reg>>2)+4*(lane>>5) ----
    float bcol[2];
#pragma unroll
    for (int ct = 0; ct < 2; ++ct) bcol[ct] = bias[w * 64 + ct * 32 + l31];
#pragma unroll
    for (int rt = 0; rt < 2; ++rt) {
#pragma unroll
        for (int reg = 0; reg < 16; ++reg) {
            const int row = m0 + rt * 32 + (reg & 3) + 8 * (reg >> 2) + 4 * lhi;
            if (row < NN) {
#pragma unroll
                for (int ct = 0; ct < 2; ++ct) {
                    const int col = w * 64 + ct * 32 + l31;
                    float v = acc[rt][ct][reg] + bcol[ct];
                    hout[((size_t)row << 8) + col] = (bf16)fmaxf(v, 0.0f);
                }
            }
        }
    }
}

// ---------------- segmented mean-pool (batch_ids sorted) ----------------
#define PCHUNK 512
__global__ __launch_bounds__(256)
void pool_kernel(const bf16* __restrict__ h, const int* __restrict__ batch_ids,
                 float* __restrict__ pooled, float* __restrict__ cnt)
{
    const int n0 = blockIdx.x * PCHUNK;
    const int f = threadIdx.x;
    __shared__ int bid_l[PCHUNK];
    for (int i = f; i < PCHUNK; i += 256) {
        int n = n0 + i;
        bid_l[i] = (n < NN) ? batch_ids[n] : -1;
    }
    __syncthreads();
    const int nEnd = (NN - n0 < PCHUNK) ? (NN - n0) : PCHUNK;
    float s = 0.0f;
    int g = bid_l[0];
    int run = 0;
    for (int i = 0; i < nEnd; ++i) {
        int bg = bid_l[i];
        if (bg != g) {
            atomicAdd(&pooled[g * HIDD + f], s);
            if (f == 0) atomicAdd(&cnt[g], (float)run);
            s = 0.0f; run = 0; g = bg;
        }
        s += (float)h[(size_t)(n0 + i) * HIDD + f];
        run++;
    }
    if (run > 0) {
        atomicAdd(&pooled[g * HIDD + f], s);
        if (f == 0) atomicAdd(&cnt[g], (float)run);
    }
}

// ---------------- MLP head ----------------
__global__ __launch_bounds__(256)
void mlp_kernel(const float* __restrict__ pooled, const float* __restrict__ cnt,
                const float* __restrict__ pW1, const float* __restrict__ pb1,
                const float* __restrict__ pW2, const float* __restrict__ pb2,
                float* __restrict__ out)
{
    const int g = blockIdx.x;
    const int d = threadIdx.x;
    __shared__ float pn[HIDD];
    __shared__ float mid[HIDD];
    float c = fmaxf(cnt[g], 1.0f);
    pn[d] = pooled[g * HIDD + d] / c;
    __syncthreads();
    float s = pb1[d];
    for (int k = 0; k < HIDD; ++k) s = fmaf(pn[k], pW1[k * HIDD + d], s);
    mid[d] = fmaxf(s, 0.0f);
    __syncthreads();
    float s2 = pb2[d];
    for (int k = 0; k < HIDD; ++k) s2 = fmaf(mid[k], pW2[k * HIDD + d], s2);
    out[g * HIDD + d] = s2;
}

extern "C" void kernel_launch(void* const* d_in, const int* in_sizes, int n_in,
                              void* d_out, int out_size, void* d_ws, size_t ws_size,
                              hipStream_t stream)
{
    const int*   x_type    = (const int*)d_in[0];
    const int*   x_sub     = (const int*)d_in[1];
    const int*   edges     = (const int*)d_in[2];
    const int*   batch_ids = (const int*)d_in[3];
    const float* type_emb  = (const float*)d_in[5];
    const float* sub_emb   = (const float*)d_in[6];
    const float* W_rel0    = (const float*)d_in[7];
    const float* W_self0   = (const float*)d_in[8];
    const float* b0        = (const float*)d_in[9];
    const float* W_rel1    = (const float*)d_in[10];
    const float* W_self1   = (const float*)d_in[11];
    const float* b1        = (const float*)d_in[12];
    const float* pW1       = (const float*)d_in[13];
    const float* pb1       = (const float*)d_in[14];
    const float* pW2       = (const float*)d_in[15];
    const float* pb2       = (const float*)d_in[16];
    float* out = (float*)d_out;

    // workspace carve-up (~108 MB)
    char* p = (char*)d_ws;
    auto carve = [&](size_t bytes) { char* q = p; p += (bytes + 255) & ~255ull; return q; };
    bf16*  h1     = (bf16*) carve((size_t)NN * HIDD * sizeof(bf16));     // layer-0 out
    bf16*  h2     = (bf16*) carve((size_t)NN * HIDD * sizeof(bf16));     // layer-1 out
    bf16*  Wf0    = (bf16*) carve((size_t)WFRAG_ELEMS * sizeof(bf16));
    bf16*  Wf1    = (bf16*) carve((size_t)WFRAG_ELEMS * sizeof(bf16));
    float* invdeg = (float*)carve((size_t)NN * sizeof(float));
    int*   hist   = (int*)  carve((size_t)NKEY * sizeof(int));
    int*   offs   = (int*)  carve((size_t)(NKEY + 1) * sizeof(int));
    int*   cursor = (int*)  carve((size_t)NKEY * sizeof(int));
    int*   bsum   = (int*)  carve(2048 * sizeof(int));
    int*   ssrc   = (int*)  carve((size_t)NEDGT * sizeof(int));
    int*   stgt   = (int*)  carve((size_t)NEDGT * sizeof(int));
    float* pooled = (float*)carve((size_t)NGR * HIDD * sizeof(float));
    float* cnt    = (float*)carve((size_t)NGR * sizeof(float));

    hipMemsetAsync(hist, 0, (size_t)NKEY * sizeof(int), stream);
    hipMemsetAsync(pooled, 0, (size_t)(NGR * HIDD + NGR) * sizeof(float), stream);

    const int NB0 = (NKEY + 2047) / 2048;  // 293
    hist_kernel<<<(NEDGT + 255) / 256, 256, 0, stream>>>(edges, hist);
    scan_l0<<<NB0, 256, 0, stream>>>(hist, offs, bsum, NKEY);
    scan_l1<<<1, 256, 0, stream>>>(bsum, NB0);
    scan_l2<<<(NKEY + 255) / 256, 256, 0, stream>>>(offs, cursor, bsum, hist, invdeg, NKEY);
    scatter_kernel<<<(NEDGT + 255) / 256, 256, 0, stream>>>(edges, cursor, ssrc, stgt);

    dim3 wgrid(7, 16, 2);
    build_wfrag<<<wgrid, 256, 0, stream>>>(W_rel0, W_self0, W_rel1, W_self1, Wf0, Wf1);

    const int FGRID = (NN + 63) / 64;   // 1563
    rgcn_fused<true><<<FGRID, 256, 0, stream>>>(h2 /*unused*/, x_type, x_sub, type_emb, sub_emb,
                                                Wf0, b0, invdeg, offs, ssrc, stgt, h1);
    rgcn_fused<false><<<FGRID, 256, 0, stream>>>(h1, x_type, x_sub, type_emb, sub_emb,
                                                 Wf1, b1, invdeg, offs, ssrc, stgt, h2);

    pool_kernel<<<(NN + PCHUNK - 1) / PCHUNK, 256, 0, stream>>>(h2, batch_ids, pooled, cnt);
    mlp_kernel<<<NGR, 256, 0, stream>>>(pooled, cnt, pW1, pb1, pW2, pb2, out);
}